// Round 1
// baseline (2658.608 us; speedup 1.0000x reference)
//
#include <hip/hip_runtime.h>
#include <hip/hip_bf16.h>

// Problem dims
#define BB 8
#define FF 512
#define SS 8192
#define HH 8
#define DD 64
#define N1 1536   // 3*H*D qkv output columns

typedef __hip_bfloat16 bf16;

__device__ __forceinline__ float us2f(unsigned short u) {
    union { unsigned int i; float f; } x; x.i = ((unsigned int)u) << 16; return x.f;
}

// ---------------------------------------------------------------------------
// K1: GroupNorm1 stats over hidden fp32 [B,F,S]; per (b,group of 16ch) -> fold
// gamma/beta into per-(b,channel) scale/shift: x_norm = h*sc + sh
// grid: 256 blocks (B*32 groups), 256 threads
__global__ void gn1_stats(const float* __restrict__ hid,
                          const float* __restrict__ gamma,
                          const float* __restrict__ beta,
                          float* __restrict__ sc, float* __restrict__ sh) {
    int bg = blockIdx.x;
    int b = bg >> 5, g = bg & 31;
    const float4* base = (const float4*)(hid + ((size_t)b * FF + g * 16) * SS);
    float s = 0.f, s2 = 0.f;
    for (int t = threadIdx.x; t < 32768; t += 256) {
        float4 x = base[t];
        s  += x.x + x.y + x.z + x.w;
        s2 += x.x * x.x + x.y * x.y + x.z * x.z + x.w * x.w;
    }
    #pragma unroll
    for (int off = 32; off > 0; off >>= 1) {
        s  += __shfl_down(s, off, 64);
        s2 += __shfl_down(s2, off, 64);
    }
    __shared__ float rs_[4], rs2_[4];
    int wid = threadIdx.x >> 6, lane = threadIdx.x & 63;
    if (lane == 0) { rs_[wid] = s; rs2_[wid] = s2; }
    __syncthreads();
    if (threadIdx.x < 16) {
        float ts  = rs_[0] + rs_[1] + rs_[2] + rs_[3];
        float ts2 = rs2_[0] + rs2_[1] + rs2_[2] + rs2_[3];
        float mu  = ts * (1.f / 131072.f);
        float var = ts2 * (1.f / 131072.f) - mu * mu;
        float r   = rsqrtf(var + 1e-8f);
        int c = g * 16 + threadIdx.x;
        float scv = gamma[c] * r;
        sc[b * FF + c] = scv;
        sh[b * FF + c] = beta[c] - mu * scv;
    }
}

// ---------------------------------------------------------------------------
// K0: transpose qkv_w [1536,512] -> Wt [512,1536]  (w flat is [j][f], j=i*512+h*64+d)
__global__ void transpose_w(const float* __restrict__ w, float* __restrict__ wt) {
    int t = blockIdx.x * 256 + threadIdx.x;   // < 786432
    int f = t & 511, j = t >> 9;
    wt[(size_t)f * N1 + j] = w[t];
}

// ---------------------------------------------------------------------------
// K2: GEMM1  qkv[b,l,n] = act( sum_f (hid[b,f,l]*sc+sh) * Wt[f,n] + bias[n] )
// A read transposed from hidden (GN1 fused). C: 64x64 tile per block, 4x4/thread.
// grid: (128, 24, 8), 256 threads
__global__ void gemm1(const float* __restrict__ hid, const float* __restrict__ Wt,
                      const float* __restrict__ sc1, const float* __restrict__ sh1,
                      const float* __restrict__ bias,
                      bf16* __restrict__ q, bf16* __restrict__ k, bf16* __restrict__ v) {
    const int b = blockIdx.z, m0 = blockIdx.x * 64, n0 = blockIdx.y * 64;
    __shared__ float As[16][68];
    __shared__ float Bs[16][68];
    float acc[4][4] = {};
    const int tid = threadIdx.x;
    const int tx = tid & 15, ty = tid >> 4;
    const int lm = tid & 63;     // l within tile (A load), n within tile (B load)
    const int lk = tid >> 6;     // k row base 0..3
    for (int k0 = 0; k0 < FF; k0 += 16) {
        #pragma unroll
        for (int ii = 0; ii < 4; ii++) {
            int kk = lk + ii * 4;
            int f = k0 + kk;
            float x = hid[((size_t)b * FF + f) * SS + m0 + lm];
            As[kk][lm] = x * sc1[b * FF + f] + sh1[b * FF + f];
            Bs[kk][lm] = Wt[(size_t)f * N1 + n0 + lm];
        }
        __syncthreads();
        #pragma unroll
        for (int kk = 0; kk < 16; kk++) {
            float a[4], bb[4];
            #pragma unroll
            for (int i = 0; i < 4; i++) a[i] = As[kk][ty * 4 + i];
            #pragma unroll
            for (int j = 0; j < 4; j++) bb[j] = Bs[kk][tx * 4 + j];
            #pragma unroll
            for (int i = 0; i < 4; i++)
                #pragma unroll
                for (int j = 0; j < 4; j++) acc[i][j] += a[i] * bb[j];
        }
        __syncthreads();
    }
    #pragma unroll
    for (int i = 0; i < 4; i++) {
        int l = m0 + ty * 4 + i;
        #pragma unroll
        for (int j = 0; j < 4; j++) {
            int n = n0 + tx * 4 + j;
            float val = acc[i][j] + bias[n];
            int which = n >> 9;          // 0=q 1=k 2=v
            int rem = n & 511;
            size_t idx = ((size_t)b * SS + l) * FF + rem;
            if (which == 2) {
                v[idx] = __float2bfloat16(val);
            } else {
                float act = val > 0.f ? val + 1.f : __expf(val);   // elu(x)+1
                (which == 0 ? q : k)[idx] = __float2bfloat16(act);
            }
        }
    }
}

// ---------------------------------------------------------------------------
// K3: kv[b,h,e,f] = sum_l k[b,l,h,f]*v[b,l,h,e]; ksum[b,h,f] = sum_l k
// grid: (64 bh, 8 s-chunks), 256 threads; atomicAdd into zeroed buffers
__global__ void kv_kernel(const bf16* __restrict__ k, const bf16* __restrict__ v,
                          float* __restrict__ kv, float* __restrict__ ksum) {
    int bh = blockIdx.x;
    int b = bh >> 3, h = bh & 7;
    int l0 = blockIdx.y * 1024;
    __shared__ float kS[16][65], vS[16][65];
    int tid = threadIdx.x;
    int f = tid & 63, eq = tid >> 6;   // eq 0..3
    float acc[16] = {};
    float ks = 0.f;
    int ll = tid >> 6, fe = tid & 63;
    for (int lc = 0; lc < 1024; lc += 16) {
        #pragma unroll
        for (int ii = 0; ii < 4; ii++) {
            int lr = ll + ii * 4;
            int l = l0 + lc + lr;
            size_t base = ((size_t)(b * SS + l)) * FF + h * DD + fe;
            kS[lr][fe] = __bfloat162float(k[base]);
            vS[lr][fe] = __bfloat162float(v[base]);
        }
        __syncthreads();
        #pragma unroll
        for (int l = 0; l < 16; l++) {
            float kf = kS[l][f];
            ks += kf;
            #pragma unroll
            for (int i = 0; i < 16; i++)
                acc[i] += kf * vS[l][eq * 16 + i];
        }
        __syncthreads();
    }
    float* kvp = kv + (size_t)bh * 4096;
    #pragma unroll
    for (int i = 0; i < 16; i++) {
        int e = eq * 16 + i;
        atomicAdd(&kvp[e * 64 + f], acc[i]);
    }
    if (eq == 0) atomicAdd(&ksum[bh * 64 + f], ks);
}

// ---------------------------------------------------------------------------
// K4: attn[b,l,h*64+e] = (sum_f q[b,l,h,f]*kv[b,h,e,f]) / (sum_f q*ksum)
// grid: (S/128, B*H), 256 threads
__global__ void attn_kernel(const bf16* __restrict__ q, const float* __restrict__ kv,
                            const float* __restrict__ ksum, bf16* __restrict__ attn) {
    int bh = blockIdx.y; int b = bh >> 3, h = bh & 7;
    int l0 = blockIdx.x * 128;
    __shared__ float kvS[64][65];
    __shared__ float qS[128][65];
    __shared__ float ksS[64];
    __shared__ float zS[128];
    int tid = threadIdx.x;
    for (int t = tid; t < 4096; t += 256) kvS[t >> 6][t & 63] = kv[(size_t)bh * 4096 + t];
    if (tid < 64) ksS[tid] = ksum[bh * 64 + tid];
    for (int t = tid; t < 8192; t += 256) {
        int l = t >> 6, f = t & 63;
        qS[l][f] = __bfloat162float(q[((size_t)(b * SS + l0 + l)) * FF + h * DD + f]);
    }
    __syncthreads();
    if (tid < 128) {
        float z = 0.f;
        #pragma unroll
        for (int f2 = 0; f2 < 64; f2++) z += qS[tid][f2] * ksS[f2];
        zS[tid] = 1.f / z;
    }
    __syncthreads();
    int e = tid & 63, lq = tid >> 6;
    for (int ii = 0; ii < 32; ii++) {
        int l = lq * 32 + ii;
        float acc = 0.f;
        #pragma unroll
        for (int f2 = 0; f2 < 64; f2++) acc += qS[l][f2] * kvS[e][f2];
        attn[((size_t)(b * SS + l0 + l)) * FF + h * DD + e] = __float2bfloat16(acc * zS[l]);
    }
}

// ---------------------------------------------------------------------------
// K5: GEMM2  y[b,n,l] = sum_f attn[b,l,f] * P[n,f]   (y stored [B,F,S] bf16)
// grid: (128, 8, 8), 256 threads
__global__ void gemm2(const bf16* __restrict__ A, const float* __restrict__ P,
                      bf16* __restrict__ y) {
    int b = blockIdx.z, m0 = blockIdx.x * 64, n0 = blockIdx.y * 64;
    __shared__ float As[16][68], Bs[16][68];
    float acc[4][4] = {};
    int tid = threadIdx.x, tx = tid & 15, ty = tid >> 4;
    int kq = tid & 15, mq = tid >> 4;
    for (int k0 = 0; k0 < FF; k0 += 16) {
        #pragma unroll
        for (int ii = 0; ii < 4; ii++) {
            int m = mq + ii * 16;
            As[kq][m] = __bfloat162float(A[((size_t)(b * SS + m0 + m)) * FF + k0 + kq]);
            Bs[kq][m] = P[((size_t)(n0 + m)) * FF + k0 + kq];
        }
        __syncthreads();
        #pragma unroll
        for (int kk = 0; kk < 16; kk++) {
            float a[4], bb[4];
            #pragma unroll
            for (int i = 0; i < 4; i++) a[i] = As[kk][ty * 4 + i];
            #pragma unroll
            for (int j = 0; j < 4; j++) bb[j] = Bs[kk][tx * 4 + j];
            #pragma unroll
            for (int i = 0; i < 4; i++)
                #pragma unroll
                for (int j = 0; j < 4; j++) acc[i][j] += a[i] * bb[j];
        }
        __syncthreads();
    }
    #pragma unroll
    for (int i = 0; i < 4; i++) {
        int l = m0 + ty * 4 + i;
        #pragma unroll
        for (int j = 0; j < 4; j++) {
            int n = n0 + tx * 4 + j;
            y[((size_t)b * FF + n) * SS + l] = __float2bfloat16(acc[i][j]);
        }
    }
}

// ---------------------------------------------------------------------------
// K6: GroupNorm2 stats over y bf16 [B,F,S]; fold gamma2/beta2 AND gate into
// per-(b,channel) gsc/gsh: out = hid + y*gsc + gsh
__global__ void gn2_stats(const bf16* __restrict__ y, const float* __restrict__ gamma,
                          const float* __restrict__ beta, const float* __restrict__ gate,
                          float* __restrict__ gsc, float* __restrict__ gsh) {
    int bg = blockIdx.x;
    int b = bg >> 5, g = bg & 31;
    const ushort4* base = (const ushort4*)(y + ((size_t)b * FF + g * 16) * SS);
    float s = 0.f, s2 = 0.f;
    for (int t = threadIdx.x; t < 32768; t += 256) {
        ushort4 u = base[t];
        float a0 = us2f(u.x), a1 = us2f(u.y), a2 = us2f(u.z), a3 = us2f(u.w);
        s  += a0 + a1 + a2 + a3;
        s2 += a0 * a0 + a1 * a1 + a2 * a2 + a3 * a3;
    }
    #pragma unroll
    for (int off = 32; off > 0; off >>= 1) {
        s  += __shfl_down(s, off, 64);
        s2 += __shfl_down(s2, off, 64);
    }
    __shared__ float rs_[4], rs2_[4];
    int wid = threadIdx.x >> 6, lane = threadIdx.x & 63;
    if (lane == 0) { rs_[wid] = s; rs2_[wid] = s2; }
    __syncthreads();
    if (threadIdx.x < 16) {
        float ts  = rs_[0] + rs_[1] + rs_[2] + rs_[3];
        float ts2 = rs2_[0] + rs2_[1] + rs2_[2] + rs2_[3];
        float mu  = ts * (1.f / 131072.f);
        float var = ts2 * (1.f / 131072.f) - mu * mu;
        float r   = rsqrtf(var + 1e-8f);
        int c = g * 16 + threadIdx.x;
        float scv = gamma[c] * r;
        gsc[b * FF + c] = gate[c] * scv;
        gsh[b * FF + c] = gate[c] * (beta[c] - mu * scv);
    }
}

// ---------------------------------------------------------------------------
// K7: out[b,f,l] = hid[b,f,l] + gsc[b,f]*y[b,f,l] + gsh[b,f]
// grid: B*F blocks (one channel-row each), 256 threads
__global__ void final_kernel(const float* __restrict__ hid, const bf16* __restrict__ y,
                             const float* __restrict__ gsc, const float* __restrict__ gsh,
                             float* __restrict__ out) {
    int bf = blockIdx.x;
    float a = gsc[bf], c0 = gsh[bf];
    const float4*  hp = (const float4*)(hid + (size_t)bf * SS);
    const ushort4* yp = (const ushort4*)(y + (size_t)bf * SS);
    float4* op = (float4*)(out + (size_t)bf * SS);
    for (int t = threadIdx.x; t < 2048; t += 256) {
        float4 hv = hp[t];
        ushort4 yv = yp[t];
        float4 r;
        r.x = hv.x + a * us2f(yv.x) + c0;
        r.y = hv.y + a * us2f(yv.y) + c0;
        r.z = hv.z + a * us2f(yv.z) + c0;
        r.w = hv.w + a * us2f(yv.w) + c0;
        op[t] = r;
    }
}

// ---------------------------------------------------------------------------
extern "C" void kernel_launch(void* const* d_in, const int* in_sizes, int n_in,
                              void* d_out, int out_size, void* d_ws, size_t ws_size,
                              hipStream_t stream) {
    const float* hid      = (const float*)d_in[0];
    const float* qkv_w    = (const float*)d_in[1];
    const float* qkv_b    = (const float*)d_in[2];
    const float* out_proj = (const float*)d_in[3];
    const float* g1       = (const float*)d_in[4];
    const float* b1       = (const float*)d_in[5];
    const float* g2       = (const float*)d_in[6];
    const float* b2       = (const float*)d_in[7];
    const float* gate     = (const float*)d_in[8];
    float* out = (float*)d_out;

    // workspace layout (~196 MB); attn aliases k (dead after kv), y aliases v
    char* p = (char*)d_ws;
    float* sc1 = (float*)p; p += (size_t)4096 * 4;
    float* sh1 = (float*)p; p += (size_t)4096 * 4;
    float* gsc = (float*)p; p += (size_t)4096 * 4;
    float* gsh = (float*)p; p += (size_t)4096 * 4;
    float* kvb = (float*)p; p += (size_t)262144 * 4;   // [B,H,D,D]
    float* ksm = (float*)p; p += (size_t)4096 * 4;     // [B,H,D]
    float* Wt  = (float*)p; p += (size_t)786432 * 4;   // [512,1536]
    bf16* qb   = (bf16*)p;  p += (size_t)33554432 * 2; // [B,S,H,D]
    bf16* kb   = (bf16*)p;  p += (size_t)33554432 * 2;
    bf16* vb   = (bf16*)p;
    bf16* attn = kb;   // alias: k dead after kv_kernel
    bf16* yb   = vb;   // alias: v dead after kv_kernel

    // zero the atomic accumulators (kv + ksum contiguous)
    hipMemsetAsync(kvb, 0, (size_t)(262144 + 4096) * 4, stream);

    gn1_stats<<<256, 256, 0, stream>>>(hid, g1, b1, sc1, sh1);
    transpose_w<<<3072, 256, 0, stream>>>(qkv_w, Wt);
    gemm1<<<dim3(128, 24, 8), 256, 0, stream>>>(hid, Wt, sc1, sh1, qkv_b, qb, kb, vb);
    kv_kernel<<<dim3(64, 8), 256, 0, stream>>>(kb, vb, kvb, ksm);
    attn_kernel<<<dim3(64, 64), 256, 0, stream>>>(qb, kvb, ksm, attn);
    gemm2<<<dim3(128, 8, 8), 256, 0, stream>>>(attn, out_proj, yb);
    gn2_stats<<<256, 256, 0, stream>>>(yb, g2, b2, gate, gsc, gsh);
    final_kernel<<<4096, 256, 0, stream>>>(hid, yb, gsc, gsh, out);
}

// Round 2
// 1047.724 us; speedup vs baseline: 2.5375x; 2.5375x over previous
//
#include <hip/hip_runtime.h>
#include <hip/hip_bf16.h>

// Problem dims
#define BB 8
#define FF 512
#define SS 8192
#define HH 8
#define DD 64
#define N1 1536   // 3*H*D qkv output columns

typedef __hip_bfloat16 bf16;
typedef __attribute__((ext_vector_type(8))) short bf16x8;
typedef __attribute__((ext_vector_type(4))) float f32x4;

__device__ __forceinline__ float us2f(unsigned short u) {
    union { unsigned int i; float f; } x; x.i = ((unsigned int)u) << 16; return x.f;
}
__device__ __forceinline__ unsigned short f2b(float f) {
    unsigned int u = __builtin_bit_cast(unsigned int, f);
    return (unsigned short)((u + 0x7FFFu + ((u >> 16) & 1u)) >> 16);   // RNE
}
__device__ __forceinline__ void gll16(const void* g, void* l) {
    __builtin_amdgcn_global_load_lds((const __attribute__((address_space(1))) void*)g,
                                     (__attribute__((address_space(3))) void*)l, 16, 0, 0);
}
// frag read with XOR k-chunk swizzle; base is LDS tile [128 rows][32 bf16], row stride 64B
__device__ __forceinline__ bf16x8 fragld(const unsigned short* base, int row, int quad) {
    int off = row * 32 + (((quad + (row >> 1)) & 3) << 3);
    return *(const bf16x8*)(base + off);
}

// ---------------------------------------------------------------------------
// GN1 stats: per (b, group of 16 ch) -> fold gamma/beta into per-(b,ch) sc/sh
__global__ void gn1_stats(const float* __restrict__ hid,
                          const float* __restrict__ gamma,
                          const float* __restrict__ beta,
                          float* __restrict__ sc, float* __restrict__ sh) {
    int bg = blockIdx.x;
    int b = bg >> 5, g = bg & 31;
    const float4* base = (const float4*)(hid + ((size_t)b * FF + g * 16) * SS);
    float s = 0.f, s2 = 0.f;
    for (int t = threadIdx.x; t < 32768; t += 256) {
        float4 x = base[t];
        s  += x.x + x.y + x.z + x.w;
        s2 += x.x * x.x + x.y * x.y + x.z * x.z + x.w * x.w;
    }
    #pragma unroll
    for (int off = 32; off > 0; off >>= 1) {
        s  += __shfl_down(s, off, 64);
        s2 += __shfl_down(s2, off, 64);
    }
    __shared__ float rs_[4], rs2_[4];
    int wid = threadIdx.x >> 6, lane = threadIdx.x & 63;
    if (lane == 0) { rs_[wid] = s; rs2_[wid] = s2; }
    __syncthreads();
    if (threadIdx.x < 16) {
        float ts  = rs_[0] + rs_[1] + rs_[2] + rs_[3];
        float ts2 = rs2_[0] + rs2_[1] + rs2_[2] + rs2_[3];
        float mu  = ts * (1.f / 131072.f);
        float var = ts2 * (1.f / 131072.f) - mu * mu;
        float r   = rsqrtf(var + 1e-8f);
        int c = g * 16 + threadIdx.x;
        float scv = gamma[c] * r;
        sc[b * FF + c] = scv;
        sh[b * FF + c] = beta[c] - mu * scv;
    }
}

// ---------------------------------------------------------------------------
// elementwise fp32 -> bf16 cast (vectorized x4)
__global__ void castb(const float* __restrict__ s, unsigned short* __restrict__ d, int n4) {
    int i = blockIdx.x * 256 + threadIdx.x;
    if (i >= n4) return;
    float4 v = ((const float4*)s)[i];
    ushort4 u = make_ushort4(f2b(v.x), f2b(v.y), f2b(v.z), f2b(v.w));
    ((ushort4*)d)[i] = u;
}

// ---------------------------------------------------------------------------
// xn_prep: xnA[b][l][f] = bf16( hid[b][f][l]*sc + sh )  (transpose via LDS)
// grid (S/64, F/64, B), 256 threads
__global__ void xn_prep(const float* __restrict__ hid, const float* __restrict__ sc,
                        const float* __restrict__ sh, unsigned short* __restrict__ xnA) {
    int b = blockIdx.z, f0 = blockIdx.y * 64, l0 = blockIdx.x * 64;
    __shared__ float t[64][65];
    int tid = threadIdx.x;
    #pragma unroll
    for (int it = 0; it < 16; it++) {
        int idx = it * 256 + tid;
        int f = idx >> 6, l = idx & 63;
        int fg = f0 + f;
        t[f][l] = hid[((size_t)b * FF + fg) * SS + l0 + l] * sc[b * FF + fg] + sh[b * FF + fg];
    }
    __syncthreads();
    #pragma unroll
    for (int it = 0; it < 4; it++) {
        int idx = it * 256 + tid;
        int l = idx >> 4, fq = (idx & 15) * 4;
        ushort4 u = make_ushort4(f2b(t[fq + 0][l]), f2b(t[fq + 1][l]),
                                 f2b(t[fq + 2][l]), f2b(t[fq + 3][l]));
        *(ushort4*)(xnA + ((size_t)b * SS + l0 + l) * FF + f0 + fq) = u;
    }
}

// ---------------------------------------------------------------------------
// GEMM1 (MFMA, swapped operands -> D[n][m]): qkv = act(xnA @ Wb^T + bias)
// A = xnA [B][S][512] bf16 (m=l,k=f), Bw = Wb [1536][512] bf16 (n,k)
// grid (S/128, N1/128, B), 256 threads
__global__ __launch_bounds__(256) void gemm1_mfma(
    const unsigned short* __restrict__ A, const unsigned short* __restrict__ Bw,
    const float* __restrict__ bias,
    unsigned short* __restrict__ q, unsigned short* __restrict__ k,
    unsigned short* __restrict__ v) {
    __shared__ unsigned short As[128 * 32] __attribute__((aligned(16)));
    __shared__ unsigned short Bs[128 * 32] __attribute__((aligned(16)));
    const int b = blockIdx.z;
    const int m0 = blockIdx.x * 128, n0 = blockIdx.y * 128;
    const int tid = threadIdx.x;
    const int w = tid >> 6, ln = tid & 63;
    const int wr = w >> 1, wc = w & 1;
    const int lrow = ln & 15, quad = ln >> 4;

    // staging: 512 chunks of 16B per tile, XOR-swizzled k-chunk within row
    const int ch0 = tid, ch1 = tid + 256;
    const int r0 = ch0 >> 2, c0 = ((ch0 & 3) - (r0 >> 1)) & 3;
    const int r1 = ch1 >> 2, c1 = ((ch1 & 3) - (r1 >> 1)) & 3;
    const unsigned short* pA0 = A + ((size_t)b * SS + m0 + r0) * FF + c0 * 8;
    const unsigned short* pA1 = A + ((size_t)b * SS + m0 + r1) * FF + c1 * 8;
    const unsigned short* pB0 = Bw + (size_t)(n0 + r0) * FF + c0 * 8;
    const unsigned short* pB1 = Bw + (size_t)(n0 + r1) * FF + c1 * 8;
    unsigned short* lA0 = As + ch0 * 8; unsigned short* lA1 = As + ch1 * 8;
    unsigned short* lB0 = Bs + ch0 * 8; unsigned short* lB1 = Bs + ch1 * 8;

    f32x4 acc[4][4];
    #pragma unroll
    for (int j = 0; j < 4; j++)
        #pragma unroll
        for (int i = 0; i < 4; i++) acc[j][i] = (f32x4){0.f, 0.f, 0.f, 0.f};

    for (int kk = 0; kk < 16; kk++) {
        gll16(pA0, lA0); gll16(pA1, lA1); gll16(pB0, lB0); gll16(pB1, lB1);
        pA0 += 32; pA1 += 32; pB0 += 32; pB1 += 32;
        __syncthreads();
        bf16x8 af[4], bm[4];
        #pragma unroll
        for (int j = 0; j < 4; j++) af[j] = fragld(Bs, wc * 64 + j * 16 + lrow, quad);
        #pragma unroll
        for (int i = 0; i < 4; i++) bm[i] = fragld(As, wr * 64 + i * 16 + lrow, quad);
        #pragma unroll
        for (int j = 0; j < 4; j++)
            #pragma unroll
            for (int i = 0; i < 4; i++)
                acc[j][i] = __builtin_amdgcn_mfma_f32_16x16x32_bf16(af[j], bm[i], acc[j][i], 0, 0, 0);
        __syncthreads();
    }
    // epilogue: D[n][m]; lane: n = base + quad*4 + r (regs), m = base + lrow
    const int n0v = n0 + wc * 64;
    const int sel = n0v >> 9;                    // 0=q 1=k 2=v (uniform per wave)
    unsigned short* outp = sel == 0 ? q : (sel == 1 ? k : v);
    const int rem0 = n0v & 511;
    const size_t mrow = (size_t)b * SS + m0 + wr * 64 + lrow;
    #pragma unroll
    for (int j = 0; j < 4; j++) {
        const float* bp = bias + n0v + j * 16 + (quad << 2);
        float b0 = bp[0], b1 = bp[1], b2 = bp[2], b3 = bp[3];
        #pragma unroll
        for (int i = 0; i < 4; i++) {
            float val0 = acc[j][i][0] + b0, val1 = acc[j][i][1] + b1;
            float val2 = acc[j][i][2] + b2, val3 = acc[j][i][3] + b3;
            if (sel < 2) {
                val0 = val0 > 0.f ? val0 + 1.f : __expf(val0);
                val1 = val1 > 0.f ? val1 + 1.f : __expf(val1);
                val2 = val2 > 0.f ? val2 + 1.f : __expf(val2);
                val3 = val3 > 0.f ? val3 + 1.f : __expf(val3);
            }
            ushort4 u = make_ushort4(f2b(val0), f2b(val1), f2b(val2), f2b(val3));
            *(ushort4*)(outp + (mrow + i * 16) * FF + rem0 + j * 16 + (quad << 2)) = u;
        }
    }
}

// ---------------------------------------------------------------------------
// GEMM2 (MFMA, normal orientation -> D[m][n]): y[b][n][l] = attn[b][l][:] @ Pb[n][:]
// transposed store: 4 consecutive l per lane
// grid (S/128, F/128, B), 256 threads
__global__ __launch_bounds__(256) void gemm2_mfma(
    const unsigned short* __restrict__ A, const unsigned short* __restrict__ Bw,
    unsigned short* __restrict__ y) {
    __shared__ unsigned short As[128 * 32] __attribute__((aligned(16)));
    __shared__ unsigned short Bs[128 * 32] __attribute__((aligned(16)));
    const int b = blockIdx.z;
    const int m0 = blockIdx.x * 128, n0 = blockIdx.y * 128;
    const int tid = threadIdx.x;
    const int w = tid >> 6, ln = tid & 63;
    const int wr = w >> 1, wc = w & 1;
    const int lrow = ln & 15, quad = ln >> 4;

    const int ch0 = tid, ch1 = tid + 256;
    const int r0 = ch0 >> 2, c0 = ((ch0 & 3) - (r0 >> 1)) & 3;
    const int r1 = ch1 >> 2, c1 = ((ch1 & 3) - (r1 >> 1)) & 3;
    const unsigned short* pA0 = A + ((size_t)b * SS + m0 + r0) * FF + c0 * 8;
    const unsigned short* pA1 = A + ((size_t)b * SS + m0 + r1) * FF + c1 * 8;
    const unsigned short* pB0 = Bw + (size_t)(n0 + r0) * FF + c0 * 8;
    const unsigned short* pB1 = Bw + (size_t)(n0 + r1) * FF + c1 * 8;
    unsigned short* lA0 = As + ch0 * 8; unsigned short* lA1 = As + ch1 * 8;
    unsigned short* lB0 = Bs + ch0 * 8; unsigned short* lB1 = Bs + ch1 * 8;

    f32x4 acc[4][4];
    #pragma unroll
    for (int i = 0; i < 4; i++)
        #pragma unroll
        for (int j = 0; j < 4; j++) acc[i][j] = (f32x4){0.f, 0.f, 0.f, 0.f};

    for (int kk = 0; kk < 16; kk++) {
        gll16(pA0, lA0); gll16(pA1, lA1); gll16(pB0, lB0); gll16(pB1, lB1);
        pA0 += 32; pA1 += 32; pB0 += 32; pB1 += 32;
        __syncthreads();
        bf16x8 am[4], bn[4];
        #pragma unroll
        for (int i = 0; i < 4; i++) am[i] = fragld(As, wr * 64 + i * 16 + lrow, quad);
        #pragma unroll
        for (int j = 0; j < 4; j++) bn[j] = fragld(Bs, wc * 64 + j * 16 + lrow, quad);
        #pragma unroll
        for (int i = 0; i < 4; i++)
            #pragma unroll
            for (int j = 0; j < 4; j++)
                acc[i][j] = __builtin_amdgcn_mfma_f32_16x16x32_bf16(am[i], bn[j], acc[i][j], 0, 0, 0);
        __syncthreads();
    }
    // D[m][n]: lane: m(l) = base + quad*4 + r, n = base + lrow
    const int nb = n0 + wc * 64 + lrow;
    const int lb0 = m0 + wr * 64 + (quad << 2);
    #pragma unroll
    for (int i = 0; i < 4; i++) {
        #pragma unroll
        for (int j = 0; j < 4; j++) {
            ushort4 u = make_ushort4(f2b(acc[i][j][0]), f2b(acc[i][j][1]),
                                     f2b(acc[i][j][2]), f2b(acc[i][j][3]));
            *(ushort4*)(y + ((size_t)b * FF + nb + j * 16) * SS + lb0 + i * 16) = u;
        }
    }
}

// ---------------------------------------------------------------------------
// K3: kv[b,h,e,f] = sum_l k[l,f]*v[l,e]; ksum[b,h,f] = sum_l k
__global__ void kv_kernel(const bf16* __restrict__ k, const bf16* __restrict__ v,
                          float* __restrict__ kv, float* __restrict__ ksum) {
    int bh = blockIdx.x;
    int b = bh >> 3, h = bh & 7;
    int l0 = blockIdx.y * 1024;
    __shared__ float kS[16][65], vS[16][65];
    int tid = threadIdx.x;
    int f = tid & 63, eq = tid >> 6;
    float acc[16] = {};
    float ks = 0.f;
    int ll = tid >> 6, fe = tid & 63;
    for (int lc = 0; lc < 1024; lc += 16) {
        #pragma unroll
        for (int ii = 0; ii < 4; ii++) {
            int lr = ll + ii * 4;
            int l = l0 + lc + lr;
            size_t base = ((size_t)(b * SS + l)) * FF + h * DD + fe;
            kS[lr][fe] = __bfloat162float(k[base]);
            vS[lr][fe] = __bfloat162float(v[base]);
        }
        __syncthreads();
        #pragma unroll
        for (int l = 0; l < 16; l++) {
            float kf = kS[l][f];
            ks += kf;
            #pragma unroll
            for (int i = 0; i < 16; i++)
                acc[i] += kf * vS[l][eq * 16 + i];
        }
        __syncthreads();
    }
    float* kvp = kv + (size_t)bh * 4096;
    #pragma unroll
    for (int i = 0; i < 16; i++) {
        int e = eq * 16 + i;
        atomicAdd(&kvp[e * 64 + f], acc[i]);
    }
    if (eq == 0) atomicAdd(&ksum[bh * 64 + f], ks);
}

// ---------------------------------------------------------------------------
// K4: attn[b,l,h*64+e] = (sum_f q*kv[e,f]) / (sum_f q*ksum)
__global__ void attn_kernel(const bf16* __restrict__ q, const float* __restrict__ kv,
                            const float* __restrict__ ksum, bf16* __restrict__ attn) {
    int bh = blockIdx.y; int b = bh >> 3, h = bh & 7;
    int l0 = blockIdx.x * 128;
    __shared__ float kvS[64][65];
    __shared__ float qS[128][65];
    __shared__ float ksS[64];
    __shared__ float zS[128];
    int tid = threadIdx.x;
    for (int t = tid; t < 4096; t += 256) kvS[t >> 6][t & 63] = kv[(size_t)bh * 4096 + t];
    if (tid < 64) ksS[tid] = ksum[bh * 64 + tid];
    for (int t = tid; t < 8192; t += 256) {
        int l = t >> 6, f = t & 63;
        qS[l][f] = __bfloat162float(q[((size_t)(b * SS + l0 + l)) * FF + h * DD + f]);
    }
    __syncthreads();
    if (tid < 128) {
        float z = 0.f;
        #pragma unroll
        for (int f2 = 0; f2 < 64; f2++) z += qS[tid][f2] * ksS[f2];
        zS[tid] = 1.f / z;
    }
    __syncthreads();
    int e = tid & 63, lq = tid >> 6;
    for (int ii = 0; ii < 32; ii++) {
        int l = lq * 32 + ii;
        float acc = 0.f;
        #pragma unroll
        for (int f2 = 0; f2 < 64; f2++) acc += qS[l][f2] * kvS[e][f2];
        attn[((size_t)(b * SS + l0 + l)) * FF + h * DD + e] = __float2bfloat16(acc * zS[l]);
    }
}

// ---------------------------------------------------------------------------
// GN2 stats + fold gate: out = hid + y*gsc + gsh
__global__ void gn2_stats(const bf16* __restrict__ y, const float* __restrict__ gamma,
                          const float* __restrict__ beta, const float* __restrict__ gate,
                          float* __restrict__ gsc, float* __restrict__ gsh) {
    int bg = blockIdx.x;
    int b = bg >> 5, g = bg & 31;
    const ushort4* base = (const ushort4*)(y + ((size_t)b * FF + g * 16) * SS);
    float s = 0.f, s2 = 0.f;
    for (int t = threadIdx.x; t < 32768; t += 256) {
        ushort4 u = base[t];
        float a0 = us2f(u.x), a1 = us2f(u.y), a2 = us2f(u.z), a3 = us2f(u.w);
        s  += a0 + a1 + a2 + a3;
        s2 += a0 * a0 + a1 * a1 + a2 * a2 + a3 * a3;
    }
    #pragma unroll
    for (int off = 32; off > 0; off >>= 1) {
        s  += __shfl_down(s, off, 64);
        s2 += __shfl_down(s2, off, 64);
    }
    __shared__ float rs_[4], rs2_[4];
    int wid = threadIdx.x >> 6, lane = threadIdx.x & 63;
    if (lane == 0) { rs_[wid] = s; rs2_[wid] = s2; }
    __syncthreads();
    if (threadIdx.x < 16) {
        float ts  = rs_[0] + rs_[1] + rs_[2] + rs_[3];
        float ts2 = rs2_[0] + rs2_[1] + rs2_[2] + rs2_[3];
        float mu  = ts * (1.f / 131072.f);
        float var = ts2 * (1.f / 131072.f) - mu * mu;
        float r   = rsqrtf(var + 1e-8f);
        int c = g * 16 + threadIdx.x;
        float scv = gamma[c] * r;
        gsc[b * FF + c] = gate[c] * scv;
        gsh[b * FF + c] = gate[c] * (beta[c] - mu * scv);
    }
}

// ---------------------------------------------------------------------------
__global__ void final_kernel(const float* __restrict__ hid, const bf16* __restrict__ y,
                             const float* __restrict__ gsc, const float* __restrict__ gsh,
                             float* __restrict__ out) {
    int bf = blockIdx.x;
    float a = gsc[bf], c0 = gsh[bf];
    const float4*  hp = (const float4*)(hid + (size_t)bf * SS);
    const ushort4* yp = (const ushort4*)(y + (size_t)bf * SS);
    float4* op = (float4*)(out + (size_t)bf * SS);
    for (int t = threadIdx.x; t < 2048; t += 256) {
        float4 hv = hp[t];
        ushort4 yv = yp[t];
        float4 r;
        r.x = hv.x + a * us2f(yv.x) + c0;
        r.y = hv.y + a * us2f(yv.y) + c0;
        r.z = hv.z + a * us2f(yv.z) + c0;
        r.w = hv.w + a * us2f(yv.w) + c0;
        op[t] = r;
    }
}

// ---------------------------------------------------------------------------
extern "C" void kernel_launch(void* const* d_in, const int* in_sizes, int n_in,
                              void* d_out, int out_size, void* d_ws, size_t ws_size,
                              hipStream_t stream) {
    const float* hid      = (const float*)d_in[0];
    const float* qkv_w    = (const float*)d_in[1];
    const float* qkv_b    = (const float*)d_in[2];
    const float* out_proj = (const float*)d_in[3];
    const float* g1       = (const float*)d_in[4];
    const float* b1       = (const float*)d_in[5];
    const float* g2       = (const float*)d_in[6];
    const float* b2       = (const float*)d_in[7];
    const float* gate     = (const float*)d_in[8];
    float* out = (float*)d_out;

    // workspace layout (~196 MB): attn aliases k, y aliases v; xnA lives in d_out
    char* p = (char*)d_ws;
    float* sc1 = (float*)p; p += (size_t)4096 * 4;
    float* sh1 = (float*)p; p += (size_t)4096 * 4;
    float* gsc = (float*)p; p += (size_t)4096 * 4;
    float* gsh = (float*)p; p += (size_t)4096 * 4;
    float* kvb = (float*)p; p += (size_t)262144 * 4;            // [B,H,D,D]
    float* ksm = (float*)p; p += (size_t)4096 * 4;              // [B,H,D]
    unsigned short* Wb = (unsigned short*)p; p += (size_t)786432 * 2;  // bf16 [1536,512]
    unsigned short* Pb = (unsigned short*)p; p += (size_t)262144 * 2;  // bf16 [512,512]
    unsigned short* qb = (unsigned short*)p; p += (size_t)33554432 * 2; // [B,S,F]
    unsigned short* kb = (unsigned short*)p; p += (size_t)33554432 * 2;
    unsigned short* vb = (unsigned short*)p;
    unsigned short* attn = kb;   // alias: k dead after kv_kernel
    unsigned short* yb   = vb;   // alias: v dead after kv_kernel
    unsigned short* xnA  = (unsigned short*)d_out;  // 64MB scratch in d_out (dead before final)

    hipMemsetAsync(kvb, 0, (size_t)(262144 + 4096) * 4, stream);

    gn1_stats<<<256, 256, 0, stream>>>(hid, g1, b1, sc1, sh1);
    castb<<<768, 256, 0, stream>>>(qkv_w, Wb, 196608);
    castb<<<256, 256, 0, stream>>>(out_proj, Pb, 65536);
    xn_prep<<<dim3(128, 8, 8), 256, 0, stream>>>(hid, sc1, sh1, xnA);
    gemm1_mfma<<<dim3(64, 12, 8), 256, 0, stream>>>(xnA, Wb, qkv_b, qb, kb, vb);
    kv_kernel<<<dim3(64, 8), 256, 0, stream>>>((const bf16*)kb, (const bf16*)vb, kvb, ksm);
    attn_kernel<<<dim3(64, 64), 256, 0, stream>>>((const bf16*)qb, kvb, ksm, (bf16*)attn);
    gemm2_mfma<<<dim3(64, 4, 8), 256, 0, stream>>>(attn, Pb, yb);
    gn2_stats<<<256, 256, 0, stream>>>((const bf16*)yb, g2, b2, gate, gsc, gsh);
    final_kernel<<<4096, 256, 0, stream>>>(hid, (const bf16*)yb, gsc, gsh, out);
}

// Round 3
// 728.403 us; speedup vs baseline: 3.6499x; 1.4384x over previous
//
#include <hip/hip_runtime.h>
#include <hip/hip_bf16.h>

// Problem dims
#define BB 8
#define FF 512
#define SS 8192
#define HH 8
#define DD 64
#define N1 1536   // 3*H*D qkv output columns

typedef __hip_bfloat16 bf16;
typedef __attribute__((ext_vector_type(8))) short bf16x8;
typedef __attribute__((ext_vector_type(4))) float f32x4;

__device__ __forceinline__ float us2f(unsigned short u) {
    union { unsigned int i; float f; } x; x.i = ((unsigned int)u) << 16; return x.f;
}
__device__ __forceinline__ unsigned short f2b(float f) {
    unsigned int u = __builtin_bit_cast(unsigned int, f);
    return (unsigned short)((u + 0x7FFFu + ((u >> 16) & 1u)) >> 16);   // RNE
}
__device__ __forceinline__ void gll16(const void* g, void* l) {
    __builtin_amdgcn_global_load_lds((const __attribute__((address_space(1))) void*)g,
                                     (__attribute__((address_space(3))) void*)l, 16, 0, 0);
}
// frag read with XOR k-chunk swizzle; base is LDS tile [128 rows][32 bf16], row stride 64B
__device__ __forceinline__ bf16x8 fragld(const unsigned short* base, int row, int quad) {
    int off = row * 32 + (((quad + (row >> 1)) & 3) << 3);
    return *(const bf16x8*)(base + off);
}

// ---------------------------------------------------------------------------
// GN1 stats: per (b, group of 16 ch) -> fold gamma/beta into per-(b,ch) sc/sh
__global__ void gn1_stats(const float* __restrict__ hid,
                          const float* __restrict__ gamma,
                          const float* __restrict__ beta,
                          float* __restrict__ sc, float* __restrict__ sh) {
    int bg = blockIdx.x;
    int b = bg >> 5, g = bg & 31;
    const float4* base = (const float4*)(hid + ((size_t)b * FF + g * 16) * SS);
    float s = 0.f, s2 = 0.f;
    for (int t = threadIdx.x; t < 32768; t += 256) {
        float4 x = base[t];
        s  += x.x + x.y + x.z + x.w;
        s2 += x.x * x.x + x.y * x.y + x.z * x.z + x.w * x.w;
    }
    #pragma unroll
    for (int off = 32; off > 0; off >>= 1) {
        s  += __shfl_down(s, off, 64);
        s2 += __shfl_down(s2, off, 64);
    }
    __shared__ float rs_[4], rs2_[4];
    int wid = threadIdx.x >> 6, lane = threadIdx.x & 63;
    if (lane == 0) { rs_[wid] = s; rs2_[wid] = s2; }
    __syncthreads();
    if (threadIdx.x < 16) {
        float ts  = rs_[0] + rs_[1] + rs_[2] + rs_[3];
        float ts2 = rs2_[0] + rs2_[1] + rs2_[2] + rs2_[3];
        float mu  = ts * (1.f / 131072.f);
        float var = ts2 * (1.f / 131072.f) - mu * mu;
        float r   = rsqrtf(var + 1e-8f);
        int c = g * 16 + threadIdx.x;
        float scv = gamma[c] * r;
        sc[b * FF + c] = scv;
        sh[b * FF + c] = beta[c] - mu * scv;
    }
}

// ---------------------------------------------------------------------------
// elementwise fp32 -> bf16 cast (vectorized x4)
__global__ void castb(const float* __restrict__ s, unsigned short* __restrict__ d, int n4) {
    int i = blockIdx.x * 256 + threadIdx.x;
    if (i >= n4) return;
    float4 v = ((const float4*)s)[i];
    ushort4 u = make_ushort4(f2b(v.x), f2b(v.y), f2b(v.z), f2b(v.w));
    ((ushort4*)d)[i] = u;
}

// ---------------------------------------------------------------------------
// xn_prep: xnA[b][l][f] = bf16( hid[b][f][l]*sc + sh )  (transpose via LDS)
__global__ void xn_prep(const float* __restrict__ hid, const float* __restrict__ sc,
                        const float* __restrict__ sh, unsigned short* __restrict__ xnA) {
    int b = blockIdx.z, f0 = blockIdx.y * 64, l0 = blockIdx.x * 64;
    __shared__ float t[64][65];
    int tid = threadIdx.x;
    #pragma unroll
    for (int it = 0; it < 16; it++) {
        int idx = it * 256 + tid;
        int f = idx >> 6, l = idx & 63;
        int fg = f0 + f;
        t[f][l] = hid[((size_t)b * FF + fg) * SS + l0 + l] * sc[b * FF + fg] + sh[b * FF + fg];
    }
    __syncthreads();
    #pragma unroll
    for (int it = 0; it < 4; it++) {
        int idx = it * 256 + tid;
        int l = idx >> 4, fq = (idx & 15) * 4;
        ushort4 u = make_ushort4(f2b(t[fq + 0][l]), f2b(t[fq + 1][l]),
                                 f2b(t[fq + 2][l]), f2b(t[fq + 3][l]));
        *(ushort4*)(xnA + ((size_t)b * SS + l0 + l) * FF + f0 + fq) = u;
    }
}

// ---------------------------------------------------------------------------
// GEMM1 (MFMA, swapped operands -> D[n][m]): qkv = act(xnA @ Wb^T + bias)
// q stored [B,S,512]; k,v stored TRANSPOSED as kT,vT [B,H,D,S] (for kv_mfma frags)
// grid (S/128, N1/128, B), 256 threads
__global__ __launch_bounds__(256) void gemm1_mfma(
    const unsigned short* __restrict__ A, const unsigned short* __restrict__ Bw,
    const float* __restrict__ bias,
    unsigned short* __restrict__ q, unsigned short* __restrict__ kT,
    unsigned short* __restrict__ vT) {
    __shared__ unsigned short As[128 * 32] __attribute__((aligned(16)));
    __shared__ unsigned short Bs[128 * 32] __attribute__((aligned(16)));
    const int b = blockIdx.z;
    const int m0 = blockIdx.x * 128, n0 = blockIdx.y * 128;
    const int tid = threadIdx.x;
    const int w = tid >> 6, ln = tid & 63;
    const int wr = w >> 1, wc = w & 1;
    const int lrow = ln & 15, quad = ln >> 4;

    const int ch0 = tid, ch1 = tid + 256;
    const int r0 = ch0 >> 2, c0 = ((ch0 & 3) - (r0 >> 1)) & 3;
    const int r1 = ch1 >> 2, c1 = ((ch1 & 3) - (r1 >> 1)) & 3;
    const unsigned short* pA0 = A + ((size_t)b * SS + m0 + r0) * FF + c0 * 8;
    const unsigned short* pA1 = A + ((size_t)b * SS + m0 + r1) * FF + c1 * 8;
    const unsigned short* pB0 = Bw + (size_t)(n0 + r0) * FF + c0 * 8;
    const unsigned short* pB1 = Bw + (size_t)(n0 + r1) * FF + c1 * 8;
    unsigned short* lA0 = As + ch0 * 8; unsigned short* lA1 = As + ch1 * 8;
    unsigned short* lB0 = Bs + ch0 * 8; unsigned short* lB1 = Bs + ch1 * 8;

    f32x4 acc[4][4];
    #pragma unroll
    for (int j = 0; j < 4; j++)
        #pragma unroll
        for (int i = 0; i < 4; i++) acc[j][i] = (f32x4){0.f, 0.f, 0.f, 0.f};

    for (int kk = 0; kk < 16; kk++) {
        gll16(pA0, lA0); gll16(pA1, lA1); gll16(pB0, lB0); gll16(pB1, lB1);
        pA0 += 32; pA1 += 32; pB0 += 32; pB1 += 32;
        __syncthreads();
        bf16x8 af[4], bm[4];
        #pragma unroll
        for (int j = 0; j < 4; j++) af[j] = fragld(Bs, wc * 64 + j * 16 + lrow, quad);
        #pragma unroll
        for (int i = 0; i < 4; i++) bm[i] = fragld(As, wr * 64 + i * 16 + lrow, quad);
        #pragma unroll
        for (int j = 0; j < 4; j++)
            #pragma unroll
            for (int i = 0; i < 4; i++)
                acc[j][i] = __builtin_amdgcn_mfma_f32_16x16x32_bf16(af[j], bm[i], acc[j][i], 0, 0, 0);
        __syncthreads();
    }
    // epilogue: D[n][m]; lane: n = n0v + j*16 + quad*4 + r, m(l) = m0 + wr*64 + lrow + i*16
    const int n0v = n0 + wc * 64;
    const int sel = n0v >> 9;                    // 0=q 1=k 2=v (uniform per wave)
    if (sel == 0) {
        const int rem0 = n0v & 511;
        const size_t mrow = (size_t)b * SS + m0 + wr * 64 + lrow;
        #pragma unroll
        for (int j = 0; j < 4; j++) {
            const float* bp = bias + n0v + j * 16 + (quad << 2);
            float b0 = bp[0], b1 = bp[1], b2 = bp[2], b3 = bp[3];
            #pragma unroll
            for (int i = 0; i < 4; i++) {
                float val0 = acc[j][i][0] + b0, val1 = acc[j][i][1] + b1;
                float val2 = acc[j][i][2] + b2, val3 = acc[j][i][3] + b3;
                val0 = val0 > 0.f ? val0 + 1.f : __expf(val0);
                val1 = val1 > 0.f ? val1 + 1.f : __expf(val1);
                val2 = val2 > 0.f ? val2 + 1.f : __expf(val2);
                val3 = val3 > 0.f ? val3 + 1.f : __expf(val3);
                ushort4 u = make_ushort4(f2b(val0), f2b(val1), f2b(val2), f2b(val3));
                *(ushort4*)(q + (mrow + i * 16) * FF + rem0 + j * 16 + (quad << 2)) = u;
            }
        }
    } else {
        // transposed store into kT/vT [B,H,D,S]; 16 consecutive-l lanes -> 32B runs
        unsigned short* outp = (sel == 1) ? kT : vT;
        const int nrel0 = (n0v & 511);
        const int lbase = m0 + wr * 64 + lrow;
        #pragma unroll
        for (int j = 0; j < 4; j++) {
            const float* bp = bias + n0v + j * 16 + (quad << 2);
            float bb4[4] = {bp[0], bp[1], bp[2], bp[3]};
            #pragma unroll
            for (int i = 0; i < 4; i++) {
                int l = lbase + i * 16;
                #pragma unroll
                for (int r = 0; r < 4; r++) {
                    float val = acc[j][i][r] + bb4[r];
                    if (sel == 1) val = val > 0.f ? val + 1.f : __expf(val);
                    int n = nrel0 + j * 16 + (quad << 2) + r;   // 0..511
                    int h = n >> 6, d = n & 63;
                    outp[(((size_t)b * HH + h) * DD + d) * SS + l] = f2b(val);
                }
            }
        }
    }
}

// ---------------------------------------------------------------------------
// kv_mfma: kv[b,h,e,f] += sum_l vT[e][l]*kT[f][l]; ksum[b,h,f] += sum_l kT[f][l]
// grid (B*H, 16 chunks of 512 l), 256 threads; atomics into zeroed fp32 buffers
__global__ __launch_bounds__(256) void kv_mfma(
    const unsigned short* __restrict__ kT, const unsigned short* __restrict__ vT,
    float* __restrict__ kv, float* __restrict__ ksum) {
    const int bh = blockIdx.x;
    const int l0 = blockIdx.y * 512;
    const int tid = threadIdx.x;

    // ksum: thread t sums 128 l of row f = t>>2
    {
        int f = tid >> 2, part = tid & 3;
        const unsigned short* kp = kT + ((size_t)bh * DD + f) * SS + l0 + part * 128;
        float s = 0.f;
        #pragma unroll
        for (int c = 0; c < 16; c++) {
            bf16x8 u = *(const bf16x8*)(kp + c * 8);
            #pragma unroll
            for (int j = 0; j < 8; j++) s += us2f((unsigned short)u[j]);
        }
        s += __shfl_down(s, 1, 64);
        s += __shfl_down(s, 2, 64);
        if (part == 0) atomicAdd(&ksum[bh * DD + f], s);
    }

    // MFMA: wave w owns e-rows [w*16, w*16+16); f = 64 (4 tiles); K = 512
    const int w = tid >> 6, ln = tid & 63;
    const int lrow = ln & 15, quad = ln >> 4;
    f32x4 acc[4];
    #pragma unroll
    for (int ft = 0; ft < 4; ft++) acc[ft] = (f32x4){0.f, 0.f, 0.f, 0.f};
    const unsigned short* vbase = vT + ((size_t)bh * DD + w * 16 + lrow) * SS + l0;
    const unsigned short* kbase = kT + ((size_t)bh * DD + lrow) * SS + l0;
    for (int ks = 0; ks < 16; ks++) {
        bf16x8 vf = *(const bf16x8*)(vbase + ks * 32 + quad * 8);
        #pragma unroll
        for (int ft = 0; ft < 4; ft++) {
            bf16x8 kf = *(const bf16x8*)(kbase + (size_t)(ft * 16) * SS + ks * 32 + quad * 8);
            acc[ft] = __builtin_amdgcn_mfma_f32_16x16x32_bf16(vf, kf, acc[ft], 0, 0, 0);
        }
    }
    float* kvp = kv + (size_t)bh * 4096;
    #pragma unroll
    for (int ft = 0; ft < 4; ft++) {
        #pragma unroll
        for (int r = 0; r < 4; r++) {
            int e = w * 16 + (quad << 2) + r;
            int f = ft * 16 + lrow;
            atomicAdd(&kvp[e * 64 + f], acc[ft][r]);
        }
    }
}

// ---------------------------------------------------------------------------
// kvcast: fp32 kv -> bf16 kv16 (same [bh][e][f] layout)
__global__ void kvcast(const float* __restrict__ kv, unsigned short* __restrict__ kv16) {
    int i = blockIdx.x * 256 + threadIdx.x;   // 65536 x float4
    float4 v = ((const float4*)kv)[i];
    ((ushort4*)kv16)[i] = make_ushort4(f2b(v.x), f2b(v.y), f2b(v.z), f2b(v.w));
}

// ---------------------------------------------------------------------------
// attn_mfma: attn[b,l,h*64+e] = (sum_f q[l,f]*kv16[e,f]) / (sum_f q[l,f]*ksum[f])
// grid (S/128, B*H), 256 threads; MFMA D[e][l], q frags direct from global
__global__ __launch_bounds__(256) void attn_mfma(
    const unsigned short* __restrict__ q, const unsigned short* __restrict__ kv16,
    const float* __restrict__ ksum, unsigned short* __restrict__ attn) {
    const int bh = blockIdx.y, b = bh >> 3, h = bh & 7;
    const int l0 = blockIdx.x * 128;
    __shared__ float ksS[64];
    __shared__ float zS[128];
    const int tid = threadIdx.x;
    if (tid < 64) ksS[tid] = ksum[bh * DD + tid];
    __syncthreads();
    if (tid < 128) {
        const unsigned short* qp = q + ((size_t)b * SS + l0 + tid) * FF + h * DD;
        float z = 0.f;
        #pragma unroll
        for (int c = 0; c < 8; c++) {
            bf16x8 u = *(const bf16x8*)(qp + c * 8);
            #pragma unroll
            for (int j = 0; j < 8; j++) z += us2f((unsigned short)u[j]) * ksS[c * 8 + j];
        }
        zS[tid] = 1.f / z;
    }
    __syncthreads();

    const int w = tid >> 6, ln = tid & 63;
    const int lrow = ln & 15, quad = ln >> 4;
    // kv fragments: rows e, k=f contiguous
    const unsigned short* kvp = kv16 + (size_t)bh * 4096;
    bf16x8 kvf[4][2];
    #pragma unroll
    for (int et = 0; et < 4; et++)
        #pragma unroll
        for (int ks = 0; ks < 2; ks++)
            kvf[et][ks] = *(const bf16x8*)(kvp + (et * 16 + lrow) * 64 + ks * 32 + quad * 8);

    f32x4 acc[2][4];
    #pragma unroll
    for (int lt = 0; lt < 2; lt++)
        #pragma unroll
        for (int et = 0; et < 4; et++) acc[lt][et] = (f32x4){0.f, 0.f, 0.f, 0.f};

    const unsigned short* qbase = q + ((size_t)b * SS + l0 + w * 32) * FF + h * DD;
    #pragma unroll
    for (int lt = 0; lt < 2; lt++) {
        #pragma unroll
        for (int ks = 0; ks < 2; ks++) {
            bf16x8 qf = *(const bf16x8*)(qbase + (size_t)(lt * 16 + lrow) * FF + ks * 32 + quad * 8);
            #pragma unroll
            for (int et = 0; et < 4; et++)
                acc[lt][et] = __builtin_amdgcn_mfma_f32_16x16x32_bf16(kvf[et][ks], qf, acc[lt][et], 0, 0, 0);
        }
    }
    // D[e][l]: lane holds e = et*16 + quad*4 + r, l = l0 + w*32 + lt*16 + lrow
    #pragma unroll
    for (int lt = 0; lt < 2; lt++) {
        int lloc = w * 32 + lt * 16 + lrow;
        float zi = zS[lloc];
        unsigned short* op = attn + ((size_t)b * SS + l0 + lloc) * FF + h * DD;
        #pragma unroll
        for (int et = 0; et < 4; et++) {
            ushort4 u = make_ushort4(f2b(acc[lt][et][0] * zi), f2b(acc[lt][et][1] * zi),
                                     f2b(acc[lt][et][2] * zi), f2b(acc[lt][et][3] * zi));
            *(ushort4*)(op + et * 16 + (quad << 2)) = u;
        }
    }
}

// ---------------------------------------------------------------------------
// GEMM2 (MFMA, normal orientation -> D[m][n]): y[b][n][l] = attn[b][l][:] @ Pb[n][:]
__global__ __launch_bounds__(256) void gemm2_mfma(
    const unsigned short* __restrict__ A, const unsigned short* __restrict__ Bw,
    unsigned short* __restrict__ y) {
    __shared__ unsigned short As[128 * 32] __attribute__((aligned(16)));
    __shared__ unsigned short Bs[128 * 32] __attribute__((aligned(16)));
    const int b = blockIdx.z;
    const int m0 = blockIdx.x * 128, n0 = blockIdx.y * 128;
    const int tid = threadIdx.x;
    const int w = tid >> 6, ln = tid & 63;
    const int wr = w >> 1, wc = w & 1;
    const int lrow = ln & 15, quad = ln >> 4;

    const int ch0 = tid, ch1 = tid + 256;
    const int r0 = ch0 >> 2, c0 = ((ch0 & 3) - (r0 >> 1)) & 3;
    const int r1 = ch1 >> 2, c1 = ((ch1 & 3) - (r1 >> 1)) & 3;
    const unsigned short* pA0 = A + ((size_t)b * SS + m0 + r0) * FF + c0 * 8;
    const unsigned short* pA1 = A + ((size_t)b * SS + m0 + r1) * FF + c1 * 8;
    const unsigned short* pB0 = Bw + (size_t)(n0 + r0) * FF + c0 * 8;
    const unsigned short* pB1 = Bw + (size_t)(n0 + r1) * FF + c1 * 8;
    unsigned short* lA0 = As + ch0 * 8; unsigned short* lA1 = As + ch1 * 8;
    unsigned short* lB0 = Bs + ch0 * 8; unsigned short* lB1 = Bs + ch1 * 8;

    f32x4 acc[4][4];
    #pragma unroll
    for (int i = 0; i < 4; i++)
        #pragma unroll
        for (int j = 0; j < 4; j++) acc[i][j] = (f32x4){0.f, 0.f, 0.f, 0.f};

    for (int kk = 0; kk < 16; kk++) {
        gll16(pA0, lA0); gll16(pA1, lA1); gll16(pB0, lB0); gll16(pB1, lB1);
        pA0 += 32; pA1 += 32; pB0 += 32; pB1 += 32;
        __syncthreads();
        bf16x8 am[4], bn[4];
        #pragma unroll
        for (int i = 0; i < 4; i++) am[i] = fragld(As, wr * 64 + i * 16 + lrow, quad);
        #pragma unroll
        for (int j = 0; j < 4; j++) bn[j] = fragld(Bs, wc * 64 + j * 16 + lrow, quad);
        #pragma unroll
        for (int i = 0; i < 4; i++)
            #pragma unroll
            for (int j = 0; j < 4; j++)
                acc[i][j] = __builtin_amdgcn_mfma_f32_16x16x32_bf16(am[i], bn[j], acc[i][j], 0, 0, 0);
        __syncthreads();
    }
    const int nb = n0 + wc * 64 + lrow;
    const int lb0 = m0 + wr * 64 + (quad << 2);
    #pragma unroll
    for (int i = 0; i < 4; i++) {
        #pragma unroll
        for (int j = 0; j < 4; j++) {
            ushort4 u = make_ushort4(f2b(acc[i][j][0]), f2b(acc[i][j][1]),
                                     f2b(acc[i][j][2]), f2b(acc[i][j][3]));
            *(ushort4*)(y + ((size_t)b * FF + nb + j * 16) * SS + lb0 + i * 16) = u;
        }
    }
}

// ---------------------------------------------------------------------------
// GN2 stats + fold gate: out = hid + y*gsc + gsh
__global__ void gn2_stats(const bf16* __restrict__ y, const float* __restrict__ gamma,
                          const float* __restrict__ beta, const float* __restrict__ gate,
                          float* __restrict__ gsc, float* __restrict__ gsh) {
    int bg = blockIdx.x;
    int b = bg >> 5, g = bg & 31;
    const ushort4* base = (const ushort4*)(y + ((size_t)b * FF + g * 16) * SS);
    float s = 0.f, s2 = 0.f;
    for (int t = threadIdx.x; t < 32768; t += 256) {
        ushort4 u = base[t];
        float a0 = us2f(u.x), a1 = us2f(u.y), a2 = us2f(u.z), a3 = us2f(u.w);
        s  += a0 + a1 + a2 + a3;
        s2 += a0 * a0 + a1 * a1 + a2 * a2 + a3 * a3;
    }
    #pragma unroll
    for (int off = 32; off > 0; off >>= 1) {
        s  += __shfl_down(s, off, 64);
        s2 += __shfl_down(s2, off, 64);
    }
    __shared__ float rs_[4], rs2_[4];
    int wid = threadIdx.x >> 6, lane = threadIdx.x & 63;
    if (lane == 0) { rs_[wid] = s; rs2_[wid] = s2; }
    __syncthreads();
    if (threadIdx.x < 16) {
        float ts  = rs_[0] + rs_[1] + rs_[2] + rs_[3];
        float ts2 = rs2_[0] + rs2_[1] + rs2_[2] + rs2_[3];
        float mu  = ts * (1.f / 131072.f);
        float var = ts2 * (1.f / 131072.f) - mu * mu;
        float r   = rsqrtf(var + 1e-8f);
        int c = g * 16 + threadIdx.x;
        float scv = gamma[c] * r;
        gsc[b * FF + c] = gate[c] * scv;
        gsh[b * FF + c] = gate[c] * (beta[c] - mu * scv);
    }
}

// ---------------------------------------------------------------------------
__global__ void final_kernel(const float* __restrict__ hid, const bf16* __restrict__ y,
                             const float* __restrict__ gsc, const float* __restrict__ gsh,
                             float* __restrict__ out) {
    int bf = blockIdx.x;
    float a = gsc[bf], c0 = gsh[bf];
    const float4*  hp = (const float4*)(hid + (size_t)bf * SS);
    const ushort4* yp = (const ushort4*)(y + (size_t)bf * SS);
    float4* op = (float4*)(out + (size_t)bf * SS);
    for (int t = threadIdx.x; t < 2048; t += 256) {
        float4 hv = hp[t];
        ushort4 yv = yp[t];
        float4 r;
        r.x = hv.x + a * us2f(yv.x) + c0;
        r.y = hv.y + a * us2f(yv.y) + c0;
        r.z = hv.z + a * us2f(yv.z) + c0;
        r.w = hv.w + a * us2f(yv.w) + c0;
        op[t] = r;
    }
}

// ---------------------------------------------------------------------------
extern "C" void kernel_launch(void* const* d_in, const int* in_sizes, int n_in,
                              void* d_out, int out_size, void* d_ws, size_t ws_size,
                              hipStream_t stream) {
    const float* hid      = (const float*)d_in[0];
    const float* qkv_w    = (const float*)d_in[1];
    const float* qkv_b    = (const float*)d_in[2];
    const float* out_proj = (const float*)d_in[3];
    const float* g1       = (const float*)d_in[4];
    const float* b1       = (const float*)d_in[5];
    const float* g2       = (const float*)d_in[6];
    const float* b2       = (const float*)d_in[7];
    const float* gate     = (const float*)d_in[8];
    float* out = (float*)d_out;

    // workspace layout (~195 MB): attn aliases kT, y aliases vT; xnA lives in d_out
    char* p = (char*)d_ws;
    float* sc1 = (float*)p; p += (size_t)4096 * 4;
    float* sh1 = (float*)p; p += (size_t)4096 * 4;
    float* gsc = (float*)p; p += (size_t)4096 * 4;
    float* gsh = (float*)p; p += (size_t)4096 * 4;
    float* kvb = (float*)p; p += (size_t)262144 * 4;            // [B,H,D,D] fp32 (atomics)
    float* ksm = (float*)p; p += (size_t)4096 * 4;              // [B,H,D] fp32 (atomics)
    unsigned short* kv16 = (unsigned short*)p; p += (size_t)262144 * 2; // bf16 kv
    unsigned short* Wb = (unsigned short*)p; p += (size_t)786432 * 2;   // bf16 [1536,512]
    unsigned short* Pb = (unsigned short*)p; p += (size_t)262144 * 2;   // bf16 [512,512]
    unsigned short* qb = (unsigned short*)p; p += (size_t)33554432 * 2; // [B,S,F]
    unsigned short* kTb = (unsigned short*)p; p += (size_t)33554432 * 2; // [B,H,D,S]
    unsigned short* vTb = (unsigned short*)p;                            // [B,H,D,S]
    unsigned short* attn = kTb;  // alias: kT dead after kv_mfma
    unsigned short* yb   = vTb;  // alias: vT dead after kv_mfma
    unsigned short* xnA  = (unsigned short*)d_out;  // 64MB scratch in d_out (dead before final)

    hipMemsetAsync(kvb, 0, (size_t)(262144 + 4096) * 4, stream);

    gn1_stats<<<256, 256, 0, stream>>>(hid, g1, b1, sc1, sh1);
    castb<<<768, 256, 0, stream>>>(qkv_w, Wb, 196608);
    castb<<<256, 256, 0, stream>>>(out_proj, Pb, 65536);
    xn_prep<<<dim3(128, 8, 8), 256, 0, stream>>>(hid, sc1, sh1, xnA);
    gemm1_mfma<<<dim3(64, 12, 8), 256, 0, stream>>>(xnA, Wb, qkv_b, qb, kTb, vTb);
    kv_mfma<<<dim3(64, 16), 256, 0, stream>>>(kTb, vTb, kvb, ksm);
    kvcast<<<256, 256, 0, stream>>>(kvb, kv16);
    attn_mfma<<<dim3(64, 64), 256, 0, stream>>>(qb, kv16, ksm, attn);
    gemm2_mfma<<<dim3(64, 4, 8), 256, 0, stream>>>(attn, Pb, yb);
    gn2_stats<<<256, 256, 0, stream>>>((const bf16*)yb, g2, b2, gate, gsc, gsh);
    final_kernel<<<4096, 256, 0, stream>>>(hid, (const bf16*)yb, gsc, gsh, out);
}